// Round 11
// baseline (221.242 us; speedup 1.0000x reference)
//
#include <hip/hip_runtime.h>

// HMULayer omega: out[b][n] = exp(-(lam_n*||x_b-mu_n||^2 + sum_k om_nk*((x_b-mu_n).v_nk)^2)/D)
// B=1024, N=8192, D=256, K=8. 9 fused bf16 MFMA GEMMs sharing A=x.
// R15: FUSE prep_w into main. Cross-round fact: non-main ~112us constant; prep_all
//      (113MB, ~23-30us serial + grid-wide dep) is the attackable part.
//  - B-tile staged ONCE per block from fp32 mu/v (147KB, reg-cvt -> swizzled
//    ds_write; 4 same-XCD blocks share the slice via L2). pw (37MB write +
//    re-read) eliminated.
//  - mu2/muv via the GEMM itself: A-frag and B-frag lane layouts are identical,
//    so mfma(bfr[0], bfr[j], amu) gives the mu.mu / mu.v cross matrix; diagonal
//    = mu2 / muv. 9 extra MFMAs/kt split over 4 waves (+7%); diag extracted
//    through a 640B LDS scratch post-loop. No wave_reduce chains.
//  - K-loop = R14's counted-vmcnt A-dbuf (proven 49us), simplified: all waves
//    issue exactly 4 glds16 -> uniform vmcnt(4). B resident, no per-kt B stage.
//  - prep_x (1MB, ~4us) kept for x2 + px.

#define B_SZ 1024
#define N_SZ 8192
#define D_SZ 256
#define K_SZ 8

#define BTM 256      // main-kernel b-tile
#define BT 128       // fallback b-tile
#define NT 16

typedef __bf16 bf16x8 __attribute__((ext_vector_type(8)));
typedef float f32x4 __attribute__((ext_vector_type(4)));
typedef unsigned short u16x4 __attribute__((ext_vector_type(4)));
typedef unsigned short u16x8 __attribute__((ext_vector_type(8)));

// ws byte offsets (R4 layout kept for fallback compat)
#define WS_X2   0u          // f32[1024]
#define WS_MU2  4096u       // f32[8192]   (fallback only)
#define WS_MUV  36864u      // f32[65536]  (fallback only)
#define WS_PX   299008u     // bf16[1024*256]   (512 KB)
#define WS_NEED_FUSED (299008ull + 524288ull)

__device__ __forceinline__ float wave_reduce(float s) {
#pragma unroll
  for (int off = 32; off > 0; off >>= 1) s += __shfl_down(s, off);
  return s;
}

__device__ __forceinline__ u16x4 cvt4(float4 t) {
  u16x4 r;
  r[0] = __builtin_bit_cast(unsigned short, (__bf16)t.x);
  r[1] = __builtin_bit_cast(unsigned short, (__bf16)t.y);
  r[2] = __builtin_bit_cast(unsigned short, (__bf16)t.z);
  r[3] = __builtin_bit_cast(unsigned short, (__bf16)t.w);
  return r;
}

__device__ __forceinline__ void glds16(const void* g, const void* l) {
  __builtin_amdgcn_global_load_lds(
      (const __attribute__((address_space(1))) void*)g,
      (__attribute__((address_space(3))) void*)l, 16, 0, 0);
}

// ---- prep_x: x2[b] + px bf16 pack. One wave per b. grid=256, block=256. ----
__global__ void prep_x(const float* __restrict__ x, float* __restrict__ x2,
                       unsigned short* __restrict__ px) {
  const int w = threadIdx.x >> 6, lane = threadIdx.x & 63;
  const int b = blockIdx.x * 4 + w;
  float4 t = *(const float4*)(x + (size_t)b * D_SZ + 4 * lane);
  *(u16x4*)(px + (size_t)b * D_SZ + 4 * lane) = cvt4(t);
  float s = t.x * t.x + t.y * t.y + t.z * t.z + t.w * t.w;
  s = wave_reduce(s);
  if (lane == 0) x2[b] = s;
}

// stage A-tile K-slab (linear LDS dest; global SOURCE chunk pre-swizzled:
// physical chunk ch holds logical chunk ch ^ ((row>>1)&3)). 4 glds16/wave.
__device__ __forceinline__ void stage_A(const unsigned short* __restrict__ px,
                                        unsigned short* As,
                                        int b0, int k0, int w, int lane) {
  const int nl4 = lane >> 2;           // row within 16
  const int ch = lane & 3;             // physical 16B chunk within 64B row
  const int kc = (ch ^ ((nl4 >> 1) & 3)) * 8;  // logical elem offset
#pragma unroll
  for (int t = 0; t < 4; ++t) {        // wave w stages rows w*64 .. w*64+63
    int r0 = w * 64 + t * 16;
    glds16(px + (size_t)(b0 + r0 + nl4) * D_SZ + k0 + kc, As + r0 * 32);
  }
}

// ---- fused main: B from fp32 mu/v (one-shot), mu2/muv via MFMA diag ----
__global__ __launch_bounds__(256, 2)
void hmu_fused(const unsigned short* __restrict__ px,
               const float* __restrict__ mu, const float* __restrict__ v,
               const float* __restrict__ lam, const float* __restrict__ om,
               const float* __restrict__ wsf, float* __restrict__ out) {
  // Bs: [kt(8)][j(9)*16+nl][32] bf16 = 72 KB (resident, swizzled)
  __shared__ __align__(16) unsigned short Bs[8 * 144 * 32];
  __shared__ __align__(16) unsigned short As[2][BTM * 32];   // 2 x 16 KB
  __shared__ float scr[16][10];                              // mu2/muv diag

  const float* ws_x2 = wsf;                    // WS_X2/4

  const int tid = threadIdx.x;
  const int lane = tid & 63;
  const int w = tid >> 6;
  const int m = lane & 15;
  const int kg = lane >> 4;

  // XCD-chunked decode (R9 proven): bid&7 = xcd, b-tile innermost.
  const int bid = blockIdx.x;
  const int xcd = bid & 7;
  const int idx = bid >> 3;                     // 0..255 within XCD
  const int n0 = (xcd * 64 + (idx >> 2)) * NT;  // n-tile
  const int b0 = (idx & 3) * BTM;               // b-tile

  // ---- one-shot B stage from fp32: wave w handles nl = w*4..w*4+3.
  // lane l covers logical elems d=4l..4l+3 of each 256-elem row:
  //   kt = l>>3, within-kt chunk c16 = (l>>1)&3, half = l&1.
  // Swizzled write: phys chunk p = c16 ^ ((nl>>1)&3)  (matches read sw).
  {
    const int ktl = lane >> 3;
    const int half = lane & 1;
    const int c16 = (lane >> 1) & 3;
#pragma unroll
    for (int nn = 0; nn < 4; ++nn) {
      const int nl = w * 4 + nn;
      const int n = n0 + nl;
      const int p = c16 ^ ((nl >> 1) & 3);
      const int base = (ktl * 144 + nl) * 32 + p * 8 + half * 4;
      float4 m4 = *(const float4*)(mu + (size_t)n * D_SZ + 4 * lane);
      *(u16x4*)(Bs + base) = cvt4(m4);
#pragma unroll
      for (int j = 1; j <= 8; ++j) {
        float4 v4 = *(const float4*)(v + ((size_t)n * K_SZ + (j - 1)) * D_SZ + 4 * lane);
        *(u16x4*)(Bs + base + j * 16 * 32) = cvt4(v4);
      }
    }
  }

  // prologue A stage (kt=0) issued after B loads (glds16 are the only
  // outstanding VMEM entering the loop after the full drain below)
  stage_A(px, As[0], b0, 0, w, lane);
  __syncthreads();   // drains vmcnt+lgkmcnt: Bs complete, As[0] complete

  f32x4 acc[4][9];
#pragma unroll
  for (int rb = 0; rb < 4; ++rb)
#pragma unroll
    for (int j = 0; j < 9; ++j) acc[rb][j] = (f32x4){0.f, 0.f, 0.f, 0.f};
  f32x4 amu[3];
#pragma unroll
  for (int t = 0; t < 3; ++t) amu[t] = (f32x4){0.f, 0.f, 0.f, 0.f};

  // read-side swizzle: logical chunk kg of row m lives at phys kg^((m>>1)&3)
  const int sw = (kg ^ ((m >> 1) & 3)) * 8;

#pragma unroll
  for (int kt = 0; kt < 8; ++kt) {
    const int cur = kt & 1;
    if (kt < 7) {
      stage_A(px, As[cur ^ 1], b0, (kt + 1) * 32, w, lane);
      asm volatile("s_waitcnt vmcnt(4)" ::: "memory");  // wait stage(kt) only
    } else {
      asm volatile("s_waitcnt vmcnt(0)" ::: "memory");
    }
    __builtin_amdgcn_s_barrier();

    const unsigned short* Ac = As[cur];
    bf16x8 bfr[9];
#pragma unroll
    for (int j = 0; j < 9; ++j)
      bfr[j] = *(const bf16x8*)&Bs[(kt * 144 + j * 16 + m) * 32 + sw];
    __builtin_amdgcn_s_setprio(1);
#pragma unroll
    for (int rb = 0; rb < 4; ++rb) {
      bf16x8 a = *(const bf16x8*)&Ac[((w * 4 + rb) * 16 + m) * 32 + sw];
#pragma unroll
      for (int j = 0; j < 9; ++j)
        acc[rb][j] = __builtin_amdgcn_mfma_f32_16x16x32_bf16(a, bfr[j], acc[rb][j], 0, 0, 0);
    }
    // mu2/muv cross-GEMM: A = mu-tile (bfr[0]); wave w owns j = w, w+4, w+8
#pragma unroll
    for (int t = 0; t < 3; ++t) {
      const int jm = w + 4 * t;
      if (jm < 9)
        amu[t] = __builtin_amdgcn_mfma_f32_16x16x32_bf16(bfr[0], bfr[jm], amu[t], 0, 0, 0);
    }
    __builtin_amdgcn_s_setprio(0);
    if (kt < 7) {
      asm volatile("s_waitcnt lgkmcnt(0)" ::: "memory");
      __builtin_amdgcn_s_barrier();   // release As[cur] for overwrite
    }
  }

  // ---- extract diag of mu-cross matrices: D row=kg*4+r, col=m; diag at
  // lanes where kg*4+r == m  ->  kg == m>>2, r == m&3 ----
#pragma unroll
  for (int t = 0; t < 3; ++t) {
    const int jm = w + 4 * t;
    if (jm < 9 && kg == (m >> 2)) scr[m][jm] = amu[t][m & 3];
  }
  __syncthreads();

  // epilogue: C/D layout col(n)=lane&15, row(b)=kg*4+reg
  const int n = n0 + m;
  const float lam_n = lam[n];
  const float mu2_n = scr[m][0];
  float omr[8], muvr[8];
#pragma unroll
  for (int k = 0; k < 8; ++k) {
    omr[k] = om[n * 8 + k];
    muvr[k] = scr[m][k + 1];
  }
#pragma unroll
  for (int rb = 0; rb < 4; ++rb) {
#pragma unroll
    for (int r = 0; r < 4; ++r) {
      int b = b0 + (w * 4 + rb) * 16 + kg * 4 + r;
      float x2b = ws_x2[b];
      float c0 = acc[rb][0][r];
      float q = lam_n * (x2b - 2.f * c0 + mu2_n);
#pragma unroll
      for (int k = 0; k < 8; ++k) {
        float p = acc[rb][k + 1][r] - muvr[k];
        q = fmaf(omr[k] * p, p, q);
      }
      out[(size_t)b * N_SZ + n] = __expf(q * (-1.0f / 256.0f));
    }
  }
}

// ================= fallback path (R2): in-loop cvt staging =================
__device__ __forceinline__ void cvt16_store(const float* __restrict__ src,
                                            unsigned short* dst) {
  const float4* p4 = (const float4*)src;
  float fv[16];
#pragma unroll
  for (int e = 0; e < 4; ++e) {
    float4 t = p4[e];
    fv[4 * e + 0] = t.x; fv[4 * e + 1] = t.y;
    fv[4 * e + 2] = t.z; fv[4 * e + 3] = t.w;
  }
  u16x8 lo, hi;
#pragma unroll
  for (int e = 0; e < 8; ++e) {
    lo[e] = __builtin_bit_cast(unsigned short, (__bf16)fv[e]);
    hi[e] = __builtin_bit_cast(unsigned short, (__bf16)fv[e + 8]);
  }
  *(u16x8*)dst = lo;
  *(u16x8*)(dst + 8) = hi;
}

#define LDS_STRIDE 40
__global__ __launch_bounds__(256, 2)
void hmu_main_f(const float* __restrict__ x, const float* __restrict__ mu,
                const float* __restrict__ lam, const float* __restrict__ v,
                const float* __restrict__ om, const float* __restrict__ ws,
                float* __restrict__ out) {
  __shared__ __align__(16) unsigned short As[BT * LDS_STRIDE];
  __shared__ __align__(16) unsigned short Bs[NT * 9 * LDS_STRIDE];
  const float* ws_x2 = ws;
  const float* ws_mu2 = ws + 1024;
  const float* ws_muv = ws + 9216;
  const int tid = threadIdx.x, lane = tid & 63, w = tid >> 6;
  const int m = lane & 15, kg = lane >> 4;
  const int n0 = blockIdx.x * NT, b0 = blockIdx.y * BT;
  f32x4 acc[2][9];
#pragma unroll
  for (int bs = 0; bs < 2; ++bs)
#pragma unroll
    for (int j = 0; j < 9; ++j) acc[bs][j] = (f32x4){0.f, 0.f, 0.f, 0.f};
  const int arow = tid >> 1, ahalf = tid & 1;
  for (int kt = 0; kt < 8; ++kt) {
    const int k0 = kt * 32;
    cvt16_store(x + (size_t)(b0 + arow) * D_SZ + k0 + ahalf * 16,
                &As[arow * LDS_STRIDE + ahalf * 16]);
#pragma unroll
    for (int it = 0; it < 2; ++it) {
      int idx = tid + 256 * it;
      if (idx < 288) {
        int row = idx >> 1, half = idx & 1;
        int nl = row / 9, j = row - nl * 9;
        const float* src = (j == 0)
            ? mu + (size_t)(n0 + nl) * D_SZ + k0 + half * 16
            : v + (size_t)((n0 + nl) * K_SZ + (j - 1)) * D_SZ + k0 + half * 16;
        cvt16_store(src, &Bs[row * LDS_STRIDE + half * 16]);
      }
    }
    __syncthreads();
    bf16x8 af[2];
#pragma unroll
    for (int bs = 0; bs < 2; ++bs)
      af[bs] = *(const bf16x8*)&As[((2 * w + bs) * 16 + m) * LDS_STRIDE + kg * 8];
#pragma unroll
    for (int j = 0; j < 9; ++j) {
      bf16x8 bfr = *(const bf16x8*)&Bs[(m * 9 + j) * LDS_STRIDE + kg * 8];
      acc[0][j] = __builtin_amdgcn_mfma_f32_16x16x32_bf16(af[0], bfr, acc[0][j], 0, 0, 0);
      acc[1][j] = __builtin_amdgcn_mfma_f32_16x16x32_bf16(af[1], bfr, acc[1][j], 0, 0, 0);
    }
    __syncthreads();
  }
  const int n = n0 + m;
  const float lam_n = lam[n];
  const float mu2_n = ws_mu2[n];
  float omr[8], muvr[8];
#pragma unroll
  for (int k = 0; k < 8; ++k) {
    omr[k] = om[n * 8 + k];
    muvr[k] = ws_muv[n * 8 + k];
  }
#pragma unroll
  for (int bs = 0; bs < 2; ++bs)
#pragma unroll
    for (int r = 0; r < 4; ++r) {
      int b = b0 + (2 * w + bs) * 16 + kg * 4 + r;
      float c0 = acc[bs][0][r];
      float q = lam_n * (ws_x2[b] - 2.f * c0 + mu2_n);
#pragma unroll
      for (int k = 0; k < 8; ++k) {
        float p = acc[bs][k + 1][r] - muvr[k];
        q = fmaf(omr[k] * p, p, q);
      }
      out[(size_t)b * N_SZ + n] = __expf(q * (-1.0f / 256.0f));
    }
}

__global__ void p2_mu_f(const float* __restrict__ mu, const float* __restrict__ v,
                        float* __restrict__ mu2, float* __restrict__ muv) {
  __shared__ __align__(16) float mulds[D_SZ];
  const int n = blockIdx.x;
  const int w = threadIdx.x >> 6, lane = threadIdx.x & 63;
  if (w == 0) {
    float4 m4 = *(const float4*)(mu + (size_t)n * D_SZ + 4 * lane);
    *(float4*)(mulds + 4 * lane) = m4;
    float s = m4.x * m4.x + m4.y * m4.y + m4.z * m4.z + m4.w * m4.w;
    s = wave_reduce(s);
    if (lane == 0) mu2[n] = s;
  }
  __syncthreads();
  float4 m4 = *(const float4*)(mulds + 4 * lane);
#pragma unroll
  for (int kk = 0; kk < 2; ++kk) {
    const int k = w * 2 + kk;
    float4 v4 = *(const float4*)(v + ((size_t)n * K_SZ + k) * D_SZ + 4 * lane);
    float s = m4.x * v4.x + m4.y * v4.y + m4.z * v4.z + m4.w * v4.w;
    s = wave_reduce(s);
    if (lane == 0) muv[n * K_SZ + k] = s;
  }
}

__global__ void p1_x2_f(const float* __restrict__ x, float* __restrict__ x2) {
  const int w = threadIdx.x >> 6, lane = threadIdx.x & 63;
  const int b = blockIdx.x * 4 + w;
  float4 t = *(const float4*)(x + (size_t)b * D_SZ + 4 * lane);
  float s = t.x * t.x + t.y * t.y + t.z * t.z + t.w * t.w;
  s = wave_reduce(s);
  if (lane == 0) x2[b] = s;
}

extern "C" void kernel_launch(void* const* d_in, const int* in_sizes, int n_in,
                              void* d_out, int out_size, void* d_ws, size_t ws_size,
                              hipStream_t stream) {
  const float* x   = (const float*)d_in[0];
  const float* mu  = (const float*)d_in[1];
  const float* lam = (const float*)d_in[2];
  const float* v   = (const float*)d_in[3];
  const float* om  = (const float*)d_in[4];
  float* out = (float*)d_out;
  char* wsb = (char*)d_ws;
  float* wsf = (float*)d_ws;
  float* x2  = (float*)(wsb + WS_X2);

  if (ws_size >= WS_NEED_FUSED) {
    unsigned short* px = (unsigned short*)(wsb + WS_PX);
    prep_x<<<B_SZ / 4, 256, 0, stream>>>(x, x2, px);
    hmu_fused<<<(N_SZ / NT) * (B_SZ / BTM), 256, 0, stream>>>(px, mu, v, lam, om, wsf, out);
  } else {
    float* mu2 = (float*)(wsb + WS_MU2);
    float* muv = (float*)(wsb + WS_MUV);
    dim3 grid(N_SZ / NT, B_SZ / BT);
    p1_x2_f<<<B_SZ / 4, 256, 0, stream>>>(x, x2);
    p2_mu_f<<<N_SZ, 256, 0, stream>>>(mu, v, mu2, muv);
    hmu_main_f<<<grid, 256, 0, stream>>>(x, mu, lam, v, om, wsf, out);
  }
}